// Round 1
// baseline (767.069 us; speedup 1.0000x reference)
//
#include <hip/hip_runtime.h>

typedef __bf16 bf16x8 __attribute__((ext_vector_type(8)));
typedef float floatx4 __attribute__((ext_vector_type(4)));

__device__ __forceinline__ unsigned short f2bf(float x) {
  union { float f; unsigned u; } v; v.f = x;
  unsigned u = v.u;
  unsigned r = (u + 0x7FFFu + ((u >> 16) & 1u)) >> 16;
  return (unsigned short)r;
}
__device__ __forceinline__ float bf2f(unsigned short x) {
  union { unsigned u; float f; } v; v.u = ((unsigned)x) << 16;
  return v.f;
}

// ---- async global->LDS staging (16B/lane, wave-uniform LDS base) ----
__device__ __forceinline__ void stage16(const unsigned short* __restrict__ g,
                                        unsigned short* s, int lane) {
#if defined(__has_builtin) && __has_builtin(__builtin_amdgcn_global_load_lds)
  __builtin_amdgcn_global_load_lds((const __attribute__((address_space(1))) void*)g,
                                   (__attribute__((address_space(3))) void*)s,
                                   16, 0, 0);
#else
  *(uint4*)(s + (size_t)lane * 8) = *(const uint4*)g;
#endif
}

// ---- fp32 -> bf16 elementwise convert (float4 loads) ----
__global__ void cvt_bf16(const float* __restrict__ in, unsigned short* __restrict__ out, int n4) {
  int i = blockIdx.x * 256 + threadIdx.x;
  if (i >= n4) return;
  const float4 v = ((const float4*)in)[i];
  ushort4 o;
  o.x = f2bf(v.x); o.y = f2bf(v.y); o.z = f2bf(v.z); o.w = f2bf(v.w);
  ((ushort4*)out)[i] = o;
}

// ---- m97-style bf16 MFMA GEMM: C[m,n] = sum_k A[m,k]*B[n,k] + bias[n] ----
// A: MxK bf16, B: NxK bf16 (row-major), C: MxN (bf16 or f32)
template <int OUT_BF16>
__global__ __launch_bounds__(256) void gemm_bt(const unsigned short* __restrict__ A,
                                               const unsigned short* __restrict__ B,
                                               const float* __restrict__ bias,
                                               void* __restrict__ Cv,
                                               int M, int N, int K) {
  __shared__ unsigned short As[128 * 32];  // 8 KB
  __shared__ unsigned short Bs[128 * 32];  // 8 KB
  const int tid = threadIdx.x;
  const int wave = tid >> 6;
  const int lane = tid & 63;
  const int bm = blockIdx.y * 128;
  const int bn = blockIdx.x * 128;
  const int wm = (wave >> 1) << 6;  // 2x2 waves, each 64x64
  const int wn = (wave & 1) << 6;

  floatx4 acc[4][4] = {};

  // staging: 8 chunks of 1024B; wave w stages chunks 2w, 2w+1
  const int c0 = wave * 2, c1 = c0 + 1;
  const int f0 = c0 * 512 + lane * 8, f1 = c1 * 512 + lane * 8;
  const int r0 = f0 >> 5, kk0 = f0 & 31;
  const int r1 = f1 >> 5, kk1 = f1 & 31;

  const unsigned short* gA0 = A + (size_t)(bm + r0) * K + kk0;
  const unsigned short* gA1 = A + (size_t)(bm + r1) * K + kk1;
  const unsigned short* gB0 = B + (size_t)(bn + r0) * K + kk0;
  const unsigned short* gB1 = B + (size_t)(bn + r1) * K + kk1;
  unsigned short* sA0 = &As[c0 * 512];
  unsigned short* sA1 = &As[c1 * 512];
  unsigned short* sB0 = &Bs[c0 * 512];
  unsigned short* sB1 = &Bs[c1 * 512];

  const int row = lane & 15, quad = lane >> 4;

  for (int kt = 0; kt < K; kt += 32) {
    __syncthreads();  // prev iter's LDS reads done before overwrite
    stage16(gA0, sA0, lane);
    stage16(gA1, sA1, lane);
    stage16(gB0, sB0, lane);
    stage16(gB1, sB1, lane);
    gA0 += 32; gA1 += 32; gB0 += 32; gB1 += 32;
    __syncthreads();  // staging drained (vmcnt(0) before barrier)

    bf16x8 af[4], bfr[4];
#pragma unroll
    for (int i = 0; i < 4; i++)
      af[i] = *(const bf16x8*)&As[(wm + i * 16 + row) * 32 + quad * 8];
#pragma unroll
    for (int j = 0; j < 4; j++)
      bfr[j] = *(const bf16x8*)&Bs[(wn + j * 16 + row) * 32 + quad * 8];
#pragma unroll
    for (int i = 0; i < 4; i++)
#pragma unroll
      for (int j = 0; j < 4; j++)
        acc[i][j] = __builtin_amdgcn_mfma_f32_16x16x32_bf16(af[i], bfr[j], acc[i][j], 0, 0, 0);
  }

  // epilogue: C/D layout col=lane&15, row=quad*4+reg (m89-verified)
#pragma unroll
  for (int j = 0; j < 4; j++) {
    const int gcol = bn + wn + j * 16 + row;
    const float bb = bias ? bias[gcol] : 0.0f;
#pragma unroll
    for (int i = 0; i < 4; i++) {
      const int grow = bm + wm + i * 16 + quad * 4;
#pragma unroll
      for (int r = 0; r < 4; r++) {
        float v = acc[i][j][r] + bb;
        if (OUT_BF16)
          ((unsigned short*)Cv)[(size_t)(grow + r) * N + gcol] = f2bf(v);
        else
          ((float*)Cv)[(size_t)(grow + r) * N + gcol] = v;
      }
    }
  }
}

// ---- causal running-mean scan, pass 1: per-chunk partial sums ----
// proj: [2][B=4][S=4096][1024] bf16; partial: [2][4][16][1024] f32
__global__ void scan_partial(const unsigned short* __restrict__ proj, float* __restrict__ partial) {
  const int cb = blockIdx.x & 3, t = blockIdx.x >> 2;
  const int c = cb * 256 + threadIdx.x;
  const int chunk = blockIdx.y, b = blockIdx.z;
  const unsigned short* p =
      proj + ((size_t)t * 4 + b) * 4096 * 1024 + (size_t)chunk * 256 * 1024 + c;
  float s = 0.f;
  for (int i = 0; i < 256; i++) s += bf2f(p[(size_t)i * 1024]);
  partial[((size_t)(t * 4 + b) * 16 + chunk) * 1024 + c] = s;
}

// ---- pass 2: apply prefix + running mean + L2-norm over head (wave=64=DK) + pack ----
// qkn: [B*S][2048] bf16, col = t*1024 + c
__global__ void scan_apply(const unsigned short* __restrict__ proj,
                           const float* __restrict__ partial,
                           unsigned short* __restrict__ qkn) {
  const int cb = blockIdx.x & 3, t = blockIdx.x >> 2;
  const int c = cb * 256 + threadIdx.x;
  const int chunk = blockIdx.y, b = blockIdx.z;
  const float* pp = partial + (size_t)(t * 4 + b) * 16 * 1024 + c;
  float run = 0.f;
  for (int j = 0; j < chunk; j++) run += pp[(size_t)j * 1024];
  const unsigned short* p =
      proj + ((size_t)t * 4 + b) * 4096 * 1024 + (size_t)chunk * 256 * 1024 + c;
  unsigned short* o = qkn + (size_t)b * 4096 * 2048 + (size_t)chunk * 256 * 2048 + t * 1024 + c;
  for (int i = 0; i < 256; i++) {
    run += bf2f(p[(size_t)i * 1024]);
    const int s = chunk * 256 + i;
    const float avg = run / (float)(s + 1);
    float sq = avg * avg;
#pragma unroll
    for (int off = 32; off; off >>= 1) sq += __shfl_xor(sq, off);  // wave(64) = one head
    const float qn = avg / fmaxf(sqrtf(sq), 1e-12f);
    o[(size_t)i * 2048] = f2bf(qn);
  }
}

// ---- tiny precomputes: A[t][h] = W(e/r)[h] @ Wc[:, t*32:+32]^T  (64x64 each) ----
__global__ void make_A(const float* __restrict__ We, const float* __restrict__ Wr,
                       const float* __restrict__ Wc, float* __restrict__ Asm) {
  const int t = blockIdx.x >> 4, h = blockIdx.x & 15;
  const float* W = (t ? Wr : We) + (size_t)h * 64 * 32;  // [64][32]
  for (int e = threadIdx.x; e < 4096; e += 256) {
    const int d = e >> 6, dk = e & 63;
    float s = 0.f;
    for (int r = 0; r < 32; r++) s += W[d * 32 + r] * Wc[dk * 64 + t * 32 + r];
    Asm[(size_t)blockIdx.x * 4096 + e] = s;
  }
}

// ---- Gt[f][t*1024+h*64+d] = sum_dk A[t][h][d][dk] * Wo[f][h*64+dk] ----
__global__ void make_G(const float* __restrict__ Asm, const float* __restrict__ Wo,
                       unsigned short* __restrict__ Gt) {
  __shared__ float Ash[4096];
  const int th = blockIdx.x, t = th >> 4, h = th & 15;
  for (int e = threadIdx.x; e < 4096; e += 256) Ash[e] = Asm[(size_t)th * 4096 + e];
  __syncthreads();
  const int f = blockIdx.y * 256 + threadIdx.x;
  float wo[64];
#pragma unroll
  for (int dk = 0; dk < 64; dk++) wo[dk] = Wo[(size_t)f * 1024 + h * 64 + dk];
  for (int d = 0; d < 64; d++) {
    float s = 0.f;
#pragma unroll
    for (int dk = 0; dk < 64; dk++) s += Ash[d * 64 + dk] * wo[dk];
    Gt[(size_t)f * 2048 + t * 1024 + h * 64 + d] = f2bf(s);
  }
}

// ---- c0[f] = bo[f] + sum_j bc[j&63]*Wo[f][j] ----
__global__ void make_c0(const float* __restrict__ bc, const float* __restrict__ bo,
                        const float* __restrict__ Wo, float* __restrict__ c0) {
  const int f = blockIdx.x * 256 + threadIdx.x;
  float s = bo[f];
  for (int j = 0; j < 1024; j++) s += bc[j & 63] * Wo[(size_t)f * 1024 + j];
  c0[f] = s;
}

extern "C" void kernel_launch(void* const* d_in, const int* in_sizes, int n_in,
                              void* d_out, int out_size, void* d_ws, size_t ws_size,
                              hipStream_t stream) {
  const float* query = (const float*)d_in[0];
  const float* key_  = (const float*)d_in[1];
  // d_in[2]=value, d_in[3]=p_layer(==1), d_in[8..9]=Wv/bv, d_in[12]=Lam: unused in p_layer branch
  const float* Wq = (const float*)d_in[4];
  const float* bq = (const float*)d_in[5];
  const float* Wk = (const float*)d_in[6];
  const float* bk = (const float*)d_in[7];
  const float* We = (const float*)d_in[10];
  const float* Wr = (const float*)d_in[11];
  const float* Wc = (const float*)d_in[13];
  const float* bc = (const float*)d_in[14];
  const float* Wo = (const float*)d_in[15];
  const float* bo = (const float*)d_in[16];

  // ws layout (~77 MB)
  char* ws = (char*)d_ws;
  unsigned short* qkbf = (unsigned short*)ws;                   // 2 x 16M bf16 = 67MB; later QKn (16384x2048)
  unsigned short* Wbf  = (unsigned short*)(ws + 67108864);      // Wq,Wk bf16: 4MB
  unsigned short* Gt   = (unsigned short*)(ws + 71303168);      // 1024x2048 bf16: 4MB
  float* partial       = (float*)(ws + 75497472);               // 2x4x16x1024 f32: 512KB
  float* Asm           = (float*)(ws + 76021760);               // 2x16x64x64 f32: 512KB
  float* c0            = (float*)(ws + 76546048);               // 4KB

  // bf16 projections live in d_out as scratch (dead before final GEMM writes)
  unsigned short* proj = (unsigned short*)d_out;

  // 1) convert activations + weights to bf16
  cvt_bf16<<<16384, 256, 0, stream>>>(query, qkbf, 4194304);
  cvt_bf16<<<16384, 256, 0, stream>>>(key_, qkbf + 16777216, 4194304);
  cvt_bf16<<<1024, 256, 0, stream>>>(Wq, Wbf, 262144);
  cvt_bf16<<<1024, 256, 0, stream>>>(Wk, Wbf + 1048576, 262144);

  // 2) q/k projections (M=16384, N=1024, K=1024) -> bf16 proj in d_out
  gemm_bt<1><<<dim3(8, 128), 256, 0, stream>>>(qkbf, Wbf, bq, proj, 16384, 1024, 1024);
  gemm_bt<1><<<dim3(8, 128), 256, 0, stream>>>(qkbf + 16777216, Wbf + 1048576, bk,
                                               proj + 16777216, 16384, 1024, 1024);

  // 3) causal running mean + l2norm + pack into QKn (over qkbf region, now dead)
  scan_partial<<<dim3(8, 16, 4), 256, 0, stream>>>(proj, partial);
  scan_apply<<<dim3(8, 16, 4), 256, 0, stream>>>(proj, partial, qkbf);

  // 4) fold We/Wr/Wc/Wo into G (2048x1024) and c0
  make_A<<<32, 256, 0, stream>>>(We, Wr, Wc, Asm);
  make_G<<<dim3(32, 4), 256, 0, stream>>>(Asm, Wo, Gt);
  make_c0<<<4, 256, 0, stream>>>(bc, bo, Wo, c0);

  // 5) out = QKn @ Gt^T + c0  (M=16384, N=1024, K=2048), fp32 out
  gemm_bt<0><<<dim3(8, 128), 256, 0, stream>>>(qkbf, Gt, c0, (float*)d_out, 16384, 1024, 2048);
}

// Round 2
// 628.104 us; speedup vs baseline: 1.2212x; 1.2212x over previous
//
#include <hip/hip_runtime.h>

typedef __bf16 bf16x8 __attribute__((ext_vector_type(8)));
typedef float floatx4 __attribute__((ext_vector_type(4)));

__device__ __forceinline__ unsigned short f2bf(float x) {
  union { float f; unsigned u; } v; v.f = x;
  unsigned u = v.u;
  unsigned r = (u + 0x7FFFu + ((u >> 16) & 1u)) >> 16;
  return (unsigned short)r;
}
__device__ __forceinline__ float bf2f(unsigned short x) {
  union { unsigned u; float f; } v; v.u = ((unsigned)x) << 16;
  return v.f;
}
__device__ __forceinline__ float fast_rcp(float x) {
#if defined(__has_builtin) && __has_builtin(__builtin_amdgcn_rcpf)
  return __builtin_amdgcn_rcpf(x);
#else
  return 1.0f / x;
#endif
}
__device__ __forceinline__ float fast_rsq(float x) {
#if defined(__has_builtin) && __has_builtin(__builtin_amdgcn_rsqf)
  return __builtin_amdgcn_rsqf(x);
#else
  return 1.0f / sqrtf(x);
#endif
}

// ---- async global->LDS staging (16B/lane, wave-uniform LDS base) ----
__device__ __forceinline__ void stage16(const unsigned short* __restrict__ g,
                                        unsigned short* s, int lane) {
#if defined(__has_builtin) && __has_builtin(__builtin_amdgcn_global_load_lds)
  __builtin_amdgcn_global_load_lds((const __attribute__((address_space(1))) void*)g,
                                   (__attribute__((address_space(3))) void*)s,
                                   16, 0, 0);
#else
  *(uint4*)(s + (size_t)lane * 8) = *(const uint4*)g;
#endif
}

// ---- fp32 -> bf16 elementwise convert (float4 loads) ----
__global__ void cvt_bf16(const float* __restrict__ in, unsigned short* __restrict__ out, int n4) {
  int i = blockIdx.x * 256 + threadIdx.x;
  if (i >= n4) return;
  const float4 v = ((const float4*)in)[i];
  ushort4 o;
  o.x = f2bf(v.x); o.y = f2bf(v.y); o.z = f2bf(v.z); o.w = f2bf(v.w);
  ((ushort4*)out)[i] = o;
}

// ---- m97-style bf16 MFMA GEMM: C[m,n] = sum_k A[m,k]*B[n,k] + bias[n] ----
template <int OUT_BF16>
__global__ __launch_bounds__(256) void gemm_bt(const unsigned short* __restrict__ A,
                                               const unsigned short* __restrict__ B,
                                               const float* __restrict__ bias,
                                               void* __restrict__ Cv,
                                               int M, int N, int K) {
  __shared__ unsigned short As[128 * 32];
  __shared__ unsigned short Bs[128 * 32];
  const int tid = threadIdx.x;
  const int wave = tid >> 6;
  const int lane = tid & 63;
  const int bm = blockIdx.y * 128;
  const int bn = blockIdx.x * 128;
  const int wm = (wave >> 1) << 6;
  const int wn = (wave & 1) << 6;

  floatx4 acc[4][4] = {};

  const int c0 = wave * 2, c1 = c0 + 1;
  const int f0 = c0 * 512 + lane * 8, f1 = c1 * 512 + lane * 8;
  const int r0 = f0 >> 5, kk0 = f0 & 31;
  const int r1 = f1 >> 5, kk1 = f1 & 31;

  const unsigned short* gA0 = A + (size_t)(bm + r0) * K + kk0;
  const unsigned short* gA1 = A + (size_t)(bm + r1) * K + kk1;
  const unsigned short* gB0 = B + (size_t)(bn + r0) * K + kk0;
  const unsigned short* gB1 = B + (size_t)(bn + r1) * K + kk1;
  unsigned short* sA0 = &As[c0 * 512];
  unsigned short* sA1 = &As[c1 * 512];
  unsigned short* sB0 = &Bs[c0 * 512];
  unsigned short* sB1 = &Bs[c1 * 512];

  const int row = lane & 15, quad = lane >> 4;

  for (int kt = 0; kt < K; kt += 32) {
    __syncthreads();
    stage16(gA0, sA0, lane);
    stage16(gA1, sA1, lane);
    stage16(gB0, sB0, lane);
    stage16(gB1, sB1, lane);
    gA0 += 32; gA1 += 32; gB0 += 32; gB1 += 32;
    __syncthreads();

    bf16x8 af[4], bfr[4];
#pragma unroll
    for (int i = 0; i < 4; i++)
      af[i] = *(const bf16x8*)&As[(wm + i * 16 + row) * 32 + quad * 8];
#pragma unroll
    for (int j = 0; j < 4; j++)
      bfr[j] = *(const bf16x8*)&Bs[(wn + j * 16 + row) * 32 + quad * 8];
#pragma unroll
    for (int i = 0; i < 4; i++)
#pragma unroll
      for (int j = 0; j < 4; j++)
        acc[i][j] = __builtin_amdgcn_mfma_f32_16x16x32_bf16(af[i], bfr[j], acc[i][j], 0, 0, 0);
  }

#pragma unroll
  for (int j = 0; j < 4; j++) {
    const int gcol = bn + wn + j * 16 + row;
    const float bb = bias ? bias[gcol] : 0.0f;
#pragma unroll
    for (int i = 0; i < 4; i++) {
      const int grow = bm + wm + i * 16 + quad * 4;
#pragma unroll
      for (int r = 0; r < 4; r++) {
        float v = acc[i][j][r] + bb;
        if (OUT_BF16)
          ((unsigned short*)Cv)[(size_t)(grow + r) * N + gcol] = f2bf(v);
        else
          ((float*)Cv)[(size_t)(grow + r) * N + gcol] = v;
      }
    }
  }
}

// ---- scan pass 1: per-chunk partial sums (64 chunks x 64 rows) ----
// proj: [2][B=4][S=4096][1024] bf16; partial: [2][4][64][1024] f32
// thread -> 4 consecutive columns (ushort4)
__global__ void scan_partial(const unsigned short* __restrict__ proj, float* __restrict__ partial) {
  const int t = blockIdx.x, chunk = blockIdx.y, b = blockIdx.z;
  const int c4 = threadIdx.x * 4;
  const unsigned short* p =
      proj + ((size_t)t * 4 + b) * 4096 * 1024 + (size_t)chunk * 64 * 1024 + c4;
  float4 s = {0.f, 0.f, 0.f, 0.f};
  for (int i = 0; i < 64; i++) {
    const ushort4 v = *(const ushort4*)(p + (size_t)i * 1024);
    s.x += bf2f(v.x); s.y += bf2f(v.y); s.z += bf2f(v.z); s.w += bf2f(v.w);
  }
  *(float4*)(partial + ((size_t)(t * 4 + b) * 64 + chunk) * 1024 + c4) = s;
}

// ---- scan pass 2: prefix + running mean + head L2-norm + pack ----
// qkn: [B*S][2048] bf16, col = t*1024 + c. Head = 64 cols = 16 lanes x 4 cols.
__global__ void scan_apply(const unsigned short* __restrict__ proj,
                           const float* __restrict__ partial,
                           unsigned short* __restrict__ qkn) {
  const int t = blockIdx.x, chunk = blockIdx.y, b = blockIdx.z;
  const int c4 = threadIdx.x * 4;
  const float* pp = partial + (size_t)(t * 4 + b) * 64 * 1024 + c4;
  float4 run = {0.f, 0.f, 0.f, 0.f};
  for (int j = 0; j < chunk; j++) {
    const float4 v = *(const float4*)(pp + (size_t)j * 1024);
    run.x += v.x; run.y += v.y; run.z += v.z; run.w += v.w;
  }
  const unsigned short* p =
      proj + ((size_t)t * 4 + b) * 4096 * 1024 + (size_t)chunk * 64 * 1024 + c4;
  unsigned short* o = qkn + (size_t)b * 4096 * 2048 + (size_t)chunk * 64 * 2048 + t * 1024 + c4;
  for (int i = 0; i < 64; i++) {
    const ushort4 v = *(const ushort4*)(p + (size_t)i * 1024);
    run.x += bf2f(v.x); run.y += bf2f(v.y); run.z += bf2f(v.z); run.w += bf2f(v.w);
    const int s = chunk * 64 + i;
    const float inv = fast_rcp((float)(s + 1));
    const float a0 = run.x * inv, a1 = run.y * inv, a2 = run.z * inv, a3 = run.w * inv;
    float sq = a0 * a0 + a1 * a1 + a2 * a2 + a3 * a3;
    sq += __shfl_xor(sq, 8);
    sq += __shfl_xor(sq, 4);
    sq += __shfl_xor(sq, 2);
    sq += __shfl_xor(sq, 1);
    const float sc = fast_rsq(fmaxf(sq, 1e-24f));
    ushort4 ov;
    ov.x = f2bf(a0 * sc); ov.y = f2bf(a1 * sc); ov.z = f2bf(a2 * sc); ov.w = f2bf(a3 * sc);
    *(ushort4*)(o + (size_t)i * 2048) = ov;
  }
}

// ---- tiny precomputes: A[t][h] = W(e/r)[h] @ Wc[:, t*32:+32]^T  (64x64 each) ----
__global__ void make_A(const float* __restrict__ We, const float* __restrict__ Wr,
                       const float* __restrict__ Wc, float* __restrict__ Asm) {
  const int t = blockIdx.x >> 4, h = blockIdx.x & 15;
  const float* W = (t ? Wr : We) + (size_t)h * 64 * 32;
  for (int e = threadIdx.x; e < 4096; e += 256) {
    const int d = e >> 6, dk = e & 63;
    float s = 0.f;
    for (int r = 0; r < 32; r++) s += W[d * 32 + r] * Wc[dk * 64 + t * 32 + r];
    Asm[(size_t)blockIdx.x * 4096 + e] = s;
  }
}

// ---- Gt[f][t*1024+h*64+d] = sum_dk A[t][h][d][dk] * Wo[f][h*64+dk] ----
__global__ void make_G(const float* __restrict__ Asm, const float* __restrict__ Wo,
                       unsigned short* __restrict__ Gt) {
  __shared__ float Ash[4096];
  const int th = blockIdx.x, t = th >> 4, h = th & 15;
  for (int e = threadIdx.x; e < 4096; e += 256) Ash[e] = Asm[(size_t)th * 4096 + e];
  __syncthreads();
  const int f = blockIdx.y * 256 + threadIdx.x;
  float wo[64];
#pragma unroll
  for (int dk = 0; dk < 64; dk++) wo[dk] = Wo[(size_t)f * 1024 + h * 64 + dk];
  for (int d = 0; d < 64; d++) {
    float s = 0.f;
#pragma unroll
    for (int dk = 0; dk < 64; dk++) s += Ash[d * 64 + dk] * wo[dk];
    Gt[(size_t)f * 2048 + t * 1024 + h * 64 + d] = f2bf(s);
  }
}

// ---- c0[f] = bo[f] + sum_j bc[j&63]*Wo[f][j]; one wave per f ----
__global__ void make_c0(const float* __restrict__ bc, const float* __restrict__ bo,
                        const float* __restrict__ Wo, float* __restrict__ c0) {
  const int f = blockIdx.x * 4 + (threadIdx.x >> 6);
  const int lane = threadIdx.x & 63;
  const float bcl = bc[lane];  // j & 63 == lane for j = lane + 64*k
  float s = 0.f;
  for (int j = lane; j < 1024; j += 64) s += bcl * Wo[(size_t)f * 1024 + j];
#pragma unroll
  for (int off = 32; off; off >>= 1) s += __shfl_xor(s, off);
  if (lane == 0) c0[f] = s + bo[f];
}

extern "C" void kernel_launch(void* const* d_in, const int* in_sizes, int n_in,
                              void* d_out, int out_size, void* d_ws, size_t ws_size,
                              hipStream_t stream) {
  const float* query = (const float*)d_in[0];
  const float* key_  = (const float*)d_in[1];
  const float* Wq = (const float*)d_in[4];
  const float* bq = (const float*)d_in[5];
  const float* Wk = (const float*)d_in[6];
  const float* bk = (const float*)d_in[7];
  const float* We = (const float*)d_in[10];
  const float* Wr = (const float*)d_in[11];
  const float* Wc = (const float*)d_in[13];
  const float* bc = (const float*)d_in[14];
  const float* Wo = (const float*)d_in[15];
  const float* bo = (const float*)d_in[16];

  // ws layout (max 76.1 MB)
  char* ws = (char*)d_ws;
  unsigned short* qkbf = (unsigned short*)ws;               // 67MB: q/k bf16, later QKn (16384x2048)
  unsigned short* Wbf  = (unsigned short*)(ws + 67108864);  // 4MB: Wq,Wk bf16
  unsigned short* Gt   = (unsigned short*)(ws + 71303168);  // 4MB: G^T (1024x2048 bf16)
  float* partial       = (float*)(ws + 71303168);           // 2MB, OVERLAYS Gt (dead before make_G)
  float* Asm           = (float*)(ws + 75497472);           // 512KB
  float* c0            = (float*)(ws + 76021760);           // 4KB

  unsigned short* proj = (unsigned short*)d_out;  // d_out as scratch for bf16 projections

  // 1) fp32 -> bf16
  cvt_bf16<<<16384, 256, 0, stream>>>(query, qkbf, 4194304);
  cvt_bf16<<<16384, 256, 0, stream>>>(key_, qkbf + 16777216, 4194304);
  cvt_bf16<<<1024, 256, 0, stream>>>(Wq, Wbf, 262144);
  cvt_bf16<<<1024, 256, 0, stream>>>(Wk, Wbf + 1048576, 262144);

  // 2) q/k projections (M=16384, N=1024, K=1024) -> bf16 proj in d_out
  gemm_bt<1><<<dim3(8, 128), 256, 0, stream>>>(qkbf, Wbf, bq, proj, 16384, 1024, 1024);
  gemm_bt<1><<<dim3(8, 128), 256, 0, stream>>>(qkbf + 16777216, Wbf + 1048576, bk,
                                               proj + 16777216, 16384, 1024, 1024);

  // 3) causal running mean + l2norm + pack into QKn
  scan_partial<<<dim3(2, 64, 4), 256, 0, stream>>>(proj, partial);
  scan_apply<<<dim3(2, 64, 4), 256, 0, stream>>>(proj, partial, qkbf);

  // 4) fold We/Wr/Wc/Wo into G (after scan: partial dead, Gt region free)
  make_A<<<32, 256, 0, stream>>>(We, Wr, Wc, Asm);
  make_G<<<dim3(32, 4), 256, 0, stream>>>(Asm, Wo, Gt);
  make_c0<<<256, 256, 0, stream>>>(bc, bo, Wo, c0);

  // 5) out = QKn @ Gt^T + c0  (M=16384, N=1024, K=2048), fp32 out
  gemm_bt<0><<<dim3(8, 128), 256, 0, stream>>>(qkbf, Gt, c0, (float*)d_out, 16384, 1024, 2048);
}

// Round 3
// 606.905 us; speedup vs baseline: 1.2639x; 1.0349x over previous
//
#include <hip/hip_runtime.h>

typedef __bf16 bf16x8 __attribute__((ext_vector_type(8)));
typedef float floatx4 __attribute__((ext_vector_type(4)));

__device__ __forceinline__ unsigned short f2bf(float x) {
  union { float f; unsigned u; } v; v.f = x;
  unsigned u = v.u;
  unsigned r = (u + 0x7FFFu + ((u >> 16) & 1u)) >> 16;
  return (unsigned short)r;
}
__device__ __forceinline__ float bf2f(unsigned short x) {
  union { unsigned u; float f; } v; v.u = ((unsigned)x) << 16;
  return v.f;
}
__device__ __forceinline__ float fast_rcp(float x) {
#if defined(__has_builtin) && __has_builtin(__builtin_amdgcn_rcpf)
  return __builtin_amdgcn_rcpf(x);
#else
  return 1.0f / x;
#endif
}
__device__ __forceinline__ float fast_rsq(float x) {
#if defined(__has_builtin) && __has_builtin(__builtin_amdgcn_rsqf)
  return __builtin_amdgcn_rsqf(x);
#else
  return 1.0f / sqrtf(x);
#endif
}

// ---- async global->LDS staging (16B/lane, wave-uniform LDS base) ----
__device__ __forceinline__ void stage16(const unsigned short* __restrict__ g,
                                        unsigned short* s, int lane) {
#if defined(__has_builtin) && __has_builtin(__builtin_amdgcn_global_load_lds)
  __builtin_amdgcn_global_load_lds((const __attribute__((address_space(1))) void*)g,
                                   (__attribute__((address_space(3))) void*)s,
                                   16, 0, 0);
#else
  *(uint4*)(s + (size_t)lane * 8) = *(const uint4*)g;
#endif
}

// ---- fp32 -> bf16 elementwise convert (float4 loads) ----
__global__ void cvt_bf16(const float* __restrict__ in, unsigned short* __restrict__ out, int n4) {
  int i = blockIdx.x * 256 + threadIdx.x;
  if (i >= n4) return;
  const float4 v = ((const float4*)in)[i];
  ushort4 o;
  o.x = f2bf(v.x); o.y = f2bf(v.y); o.z = f2bf(v.z); o.w = f2bf(v.w);
  ((ushort4*)out)[i] = o;
}

// ---- m97-style bf16 MFMA GEMM: C[m,n] = sum_k A[m,k]*B[n,k] + bias[n] ----
// 1-D grid of (M/128)*(N/128) blocks. Block->tile mapping is XCD-swizzled:
// id = x + 8*(nt + NT*gm), mt = x + 8*gm  =>  all 8 n-tiles of an m-tile share
// id%8 (same XCD under round-robin) -> A-stripe reused from that XCD's L2.
template <int OUT_BF16>
__global__ __launch_bounds__(256) void gemm_bt(const unsigned short* __restrict__ A,
                                               const unsigned short* __restrict__ B,
                                               const float* __restrict__ bias,
                                               void* __restrict__ Cv,
                                               int M, int N, int K) {
  __shared__ unsigned short As[128 * 32];
  __shared__ unsigned short Bs[128 * 32];
  const int tid = threadIdx.x;
  const int wave = tid >> 6;
  const int lane = tid & 63;

  const int NT = N >> 7;
  const int id = blockIdx.x;
  const int x = id & 7;
  const int g = id >> 3;
  const int nt = g % NT;
  const int mt = x + 8 * (g / NT);
  const int bm = mt * 128;
  const int bn = nt * 128;

  const int wm = (wave >> 1) << 6;
  const int wn = (wave & 1) << 6;

  floatx4 acc[4][4] = {};

  const int c0 = wave * 2, c1 = c0 + 1;
  const int f0 = c0 * 512 + lane * 8, f1 = c1 * 512 + lane * 8;
  const int r0 = f0 >> 5, kk0 = f0 & 31;
  const int r1 = f1 >> 5, kk1 = f1 & 31;

  const unsigned short* gA0 = A + (size_t)(bm + r0) * K + kk0;
  const unsigned short* gA1 = A + (size_t)(bm + r1) * K + kk1;
  const unsigned short* gB0 = B + (size_t)(bn + r0) * K + kk0;
  const unsigned short* gB1 = B + (size_t)(bn + r1) * K + kk1;
  unsigned short* sA0 = &As[c0 * 512];
  unsigned short* sA1 = &As[c1 * 512];
  unsigned short* sB0 = &Bs[c0 * 512];
  unsigned short* sB1 = &Bs[c1 * 512];

  const int row = lane & 15, quad = lane >> 4;

  for (int kt = 0; kt < K; kt += 32) {
    __syncthreads();
    stage16(gA0, sA0, lane);
    stage16(gA1, sA1, lane);
    stage16(gB0, sB0, lane);
    stage16(gB1, sB1, lane);
    gA0 += 32; gA1 += 32; gB0 += 32; gB1 += 32;
    __syncthreads();

    bf16x8 af[4], bfr[4];
#pragma unroll
    for (int i = 0; i < 4; i++)
      af[i] = *(const bf16x8*)&As[(wm + i * 16 + row) * 32 + quad * 8];
#pragma unroll
    for (int j = 0; j < 4; j++)
      bfr[j] = *(const bf16x8*)&Bs[(wn + j * 16 + row) * 32 + quad * 8];
#pragma unroll
    for (int i = 0; i < 4; i++)
#pragma unroll
      for (int j = 0; j < 4; j++)
        acc[i][j] = __builtin_amdgcn_mfma_f32_16x16x32_bf16(af[i], bfr[j], acc[i][j], 0, 0, 0);
  }

#pragma unroll
  for (int j = 0; j < 4; j++) {
    const int gcol = bn + wn + j * 16 + row;
    const float bb = bias ? bias[gcol] : 0.0f;
#pragma unroll
    for (int i = 0; i < 4; i++) {
      const int grow = bm + wm + i * 16 + quad * 4;
#pragma unroll
      for (int r = 0; r < 4; r++) {
        float v = acc[i][j][r] + bb;
        if (OUT_BF16)
          ((unsigned short*)Cv)[(size_t)(grow + r) * N + gcol] = f2bf(v);
        else
          ((float*)Cv)[(size_t)(grow + r) * N + gcol] = v;
      }
    }
  }
}

// ---- scan pass 1: per-chunk partial sums (64 chunks x 64 rows) ----
// proj: [2][B=4][S=4096][1024] bf16; partial: [2][4][64][1024] f32
__global__ void scan_partial(const unsigned short* __restrict__ proj, float* __restrict__ partial) {
  const int t = blockIdx.x, chunk = blockIdx.y, b = blockIdx.z;
  const int c4 = threadIdx.x * 4;
  const unsigned short* p =
      proj + ((size_t)t * 4 + b) * 4096 * 1024 + (size_t)chunk * 64 * 1024 + c4;
  float4 s = {0.f, 0.f, 0.f, 0.f};
  for (int i = 0; i < 64; i++) {
    const ushort4 v = *(const ushort4*)(p + (size_t)i * 1024);
    s.x += bf2f(v.x); s.y += bf2f(v.y); s.z += bf2f(v.z); s.w += bf2f(v.w);
  }
  *(float4*)(partial + ((size_t)(t * 4 + b) * 64 + chunk) * 1024 + c4) = s;
}

// ---- scan pass 2: prefix + running mean + head L2-norm + pack ----
// qkn: [B*S][2048] bf16, col = t*1024 + c. Head = 64 cols = 16 lanes x 4 cols.
__global__ void scan_apply(const unsigned short* __restrict__ proj,
                           const float* __restrict__ partial,
                           unsigned short* __restrict__ qkn) {
  const int t = blockIdx.x, chunk = blockIdx.y, b = blockIdx.z;
  const int c4 = threadIdx.x * 4;
  const float* pp = partial + (size_t)(t * 4 + b) * 64 * 1024 + c4;
  float4 run = {0.f, 0.f, 0.f, 0.f};
  for (int j = 0; j < chunk; j++) {
    const float4 v = *(const float4*)(pp + (size_t)j * 1024);
    run.x += v.x; run.y += v.y; run.z += v.z; run.w += v.w;
  }
  const unsigned short* p =
      proj + ((size_t)t * 4 + b) * 4096 * 1024 + (size_t)chunk * 64 * 1024 + c4;
  unsigned short* o = qkn + (size_t)b * 4096 * 2048 + (size_t)chunk * 64 * 2048 + t * 1024 + c4;
  for (int i = 0; i < 64; i++) {
    const ushort4 v = *(const ushort4*)(p + (size_t)i * 1024);
    run.x += bf2f(v.x); run.y += bf2f(v.y); run.z += bf2f(v.z); run.w += bf2f(v.w);
    const int s = chunk * 64 + i;
    const float inv = fast_rcp((float)(s + 1));
    const float a0 = run.x * inv, a1 = run.y * inv, a2 = run.z * inv, a3 = run.w * inv;
    float sq = a0 * a0 + a1 * a1 + a2 * a2 + a3 * a3;
    sq += __shfl_xor(sq, 8);
    sq += __shfl_xor(sq, 4);
    sq += __shfl_xor(sq, 2);
    sq += __shfl_xor(sq, 1);
    const float sc = fast_rsq(fmaxf(sq, 1e-24f));
    ushort4 ov;
    ov.x = f2bf(a0 * sc); ov.y = f2bf(a1 * sc); ov.z = f2bf(a2 * sc); ov.w = f2bf(a3 * sc);
    *(ushort4*)(o + (size_t)i * 2048) = ov;
  }
}

// ---- tiny precomputes: A[t][h] = W(e/r)[h] @ Wc[:, t*32:+32]^T  (64x64 each) ----
__global__ void make_A(const float* __restrict__ We, const float* __restrict__ Wr,
                       const float* __restrict__ Wc, float* __restrict__ Asm) {
  const int t = blockIdx.x >> 4, h = blockIdx.x & 15;
  const float* W = (t ? Wr : We) + (size_t)h * 64 * 32;
  for (int e = threadIdx.x; e < 4096; e += 256) {
    const int d = e >> 6, dk = e & 63;
    float s = 0.f;
    for (int r = 0; r < 32; r++) s += W[d * 32 + r] * Wc[dk * 64 + t * 32 + r];
    Asm[(size_t)blockIdx.x * 4096 + e] = s;
  }
}

// ---- Gt[f][t*1024+h*64+d] = sum_dk A[t][h][d][dk] * Wo[f][h*64+dk] ----
__global__ void make_G(const float* __restrict__ Asm, const float* __restrict__ Wo,
                       unsigned short* __restrict__ Gt) {
  __shared__ float Ash[4096];
  const int th = blockIdx.x, t = th >> 4, h = th & 15;
  for (int e = threadIdx.x; e < 4096; e += 256) Ash[e] = Asm[(size_t)th * 4096 + e];
  __syncthreads();
  const int f = blockIdx.y * 256 + threadIdx.x;
  float wo[64];
#pragma unroll
  for (int dk = 0; dk < 64; dk++) wo[dk] = Wo[(size_t)f * 1024 + h * 64 + dk];
  for (int d = 0; d < 64; d++) {
    float s = 0.f;
#pragma unroll
    for (int dk = 0; dk < 64; dk++) s += Ash[d * 64 + dk] * wo[dk];
    Gt[(size_t)f * 2048 + t * 1024 + h * 64 + d] = f2bf(s);
  }
}

// ---- c0[f] = bo[f] + sum_j bc[j&63]*Wo[f][j]; one wave per f ----
__global__ void make_c0(const float* __restrict__ bc, const float* __restrict__ bo,
                        const float* __restrict__ Wo, float* __restrict__ c0) {
  const int f = blockIdx.x * 4 + (threadIdx.x >> 6);
  const int lane = threadIdx.x & 63;
  const float bcl = bc[lane];
  float s = 0.f;
  for (int j = lane; j < 1024; j += 64) s += bcl * Wo[(size_t)f * 1024 + j];
#pragma unroll
  for (int off = 32; off; off >>= 1) s += __shfl_xor(s, off);
  if (lane == 0) c0[f] = s + bo[f];
}

extern "C" void kernel_launch(void* const* d_in, const int* in_sizes, int n_in,
                              void* d_out, int out_size, void* d_ws, size_t ws_size,
                              hipStream_t stream) {
  const float* query = (const float*)d_in[0];
  const float* key_  = (const float*)d_in[1];
  const float* Wq = (const float*)d_in[4];
  const float* bq = (const float*)d_in[5];
  const float* Wk = (const float*)d_in[6];
  const float* bk = (const float*)d_in[7];
  const float* We = (const float*)d_in[10];
  const float* Wr = (const float*)d_in[11];
  const float* Wc = (const float*)d_in[13];
  const float* bc = (const float*)d_in[14];
  const float* Wo = (const float*)d_in[15];
  const float* bo = (const float*)d_in[16];

  // ws layout (max 76.1 MB)
  char* ws = (char*)d_ws;
  unsigned short* qkbf = (unsigned short*)ws;               // 67MB: q/k bf16, later QKn (16384x2048)
  unsigned short* Wbf  = (unsigned short*)(ws + 67108864);  // 4MB: Wq,Wk bf16
  unsigned short* Gt   = (unsigned short*)(ws + 71303168);  // 4MB: G^T (1024x2048 bf16)
  float* partial       = (float*)(ws + 71303168);           // 2MB, OVERLAYS Gt (dead before make_G)
  float* Asm           = (float*)(ws + 75497472);           // 512KB
  float* c0            = (float*)(ws + 76021760);           // 4KB

  unsigned short* proj = (unsigned short*)d_out;  // d_out as scratch for bf16 projections

  // 1) fp32 -> bf16
  cvt_bf16<<<16384, 256, 0, stream>>>(query, qkbf, 4194304);
  cvt_bf16<<<16384, 256, 0, stream>>>(key_, qkbf + 16777216, 4194304);
  cvt_bf16<<<1024, 256, 0, stream>>>(Wq, Wbf, 262144);
  cvt_bf16<<<1024, 256, 0, stream>>>(Wk, Wbf + 1048576, 262144);

  // 2) q/k projections (M=16384, N=1024, K=1024) -> bf16 proj in d_out
  gemm_bt<1><<<1024, 256, 0, stream>>>(qkbf, Wbf, bq, proj, 16384, 1024, 1024);
  gemm_bt<1><<<1024, 256, 0, stream>>>(qkbf + 16777216, Wbf + 1048576, bk,
                                       proj + 16777216, 16384, 1024, 1024);

  // 3) causal running mean + l2norm + pack into QKn
  scan_partial<<<dim3(2, 64, 4), 256, 0, stream>>>(proj, partial);
  scan_apply<<<dim3(2, 64, 4), 256, 0, stream>>>(proj, partial, qkbf);

  // 4) fold We/Wr/Wc/Wo into G (after scan: partial dead, Gt region free)
  make_A<<<32, 256, 0, stream>>>(We, Wr, Wc, Asm);
  make_G<<<dim3(32, 4), 256, 0, stream>>>(Asm, Wo, Gt);
  make_c0<<<256, 256, 0, stream>>>(bc, bo, Wo, c0);

  // 5) out = QKn @ Gt^T + c0  (M=16384, N=1024, K=2048), fp32 out
  gemm_bt<0><<<1024, 256, 0, stream>>>(qkbf, Gt, c0, (float*)d_out, 16384, 1024, 2048);
}

// Round 4
// 568.191 us; speedup vs baseline: 1.3500x; 1.0681x over previous
//
#include <hip/hip_runtime.h>

typedef __bf16 bf16x8 __attribute__((ext_vector_type(8)));
typedef float floatx4 __attribute__((ext_vector_type(4)));

__device__ __forceinline__ unsigned short f2bf(float x) {
  union { float f; unsigned u; } v; v.f = x;
  unsigned u = v.u;
  unsigned r = (u + 0x7FFFu + ((u >> 16) & 1u)) >> 16;
  return (unsigned short)r;
}
__device__ __forceinline__ float bf2f(unsigned short x) {
  union { unsigned u; float f; } v; v.u = ((unsigned)x) << 16;
  return v.f;
}
__device__ __forceinline__ float fast_rcp(float x) {
#if defined(__has_builtin) && __has_builtin(__builtin_amdgcn_rcpf)
  return __builtin_amdgcn_rcpf(x);
#else
  return 1.0f / x;
#endif
}
__device__ __forceinline__ float fast_rsq(float x) {
#if defined(__has_builtin) && __has_builtin(__builtin_amdgcn_rsqf)
  return __builtin_amdgcn_rsqf(x);
#else
  return 1.0f / sqrtf(x);
#endif
}

// ---- async global->LDS staging (16B/lane, wave-uniform LDS base) ----
__device__ __forceinline__ void stage16(const unsigned short* __restrict__ g,
                                        unsigned short* s, int lane) {
#if defined(__has_builtin) && __has_builtin(__builtin_amdgcn_global_load_lds)
  __builtin_amdgcn_global_load_lds((const __attribute__((address_space(1))) void*)g,
                                   (__attribute__((address_space(3))) void*)s,
                                   16, 0, 0);
#else
  *(uint4*)(s + (size_t)lane * 8) = *(const uint4*)g;
#endif
}

// ---- fp32 -> bf16 elementwise convert (float4 loads) ----
__global__ void cvt_bf16(const float* __restrict__ in, unsigned short* __restrict__ out, int n4) {
  int i = blockIdx.x * 256 + threadIdx.x;
  if (i >= n4) return;
  const float4 v = ((const float4*)in)[i];
  ushort4 o;
  o.x = f2bf(v.x); o.y = f2bf(v.y); o.z = f2bf(v.z); o.w = f2bf(v.w);
  ((ushort4*)out)[i] = o;
}

// ---- bf16 MFMA GEMM, BK=64, XOR-swizzled LDS k-groups ----
// C[m,n] = sum_k A[m,k]*B[n,k] + bias[n].
// LDS physical layout: As[row][p*8..p*8+7] holds global k-group g = p ^ (row&7)
// (16B granules). Staging side: lane l of chunk c loads global
// (row = 8c + l/8, kg = (l&7)^(l/8)) -> lands at physical p = l&7.  Fragment
// reads use p = (s*4+q) ^ (lane&7). Keeps global coalescing (permute within a
// 128B row) and the 8-phase b128 LDS floor (row stride 128B alone would be
// 16-way conflicted).
// Grid: 1-D, XCD-swizzled: id = x + 8*(nt + NT*gm), mt = x + 8*gm.
template <int OUT_BF16>
__global__ __launch_bounds__(256) void gemm_bt(const unsigned short* __restrict__ A,
                                               const unsigned short* __restrict__ B,
                                               const float* __restrict__ bias,
                                               void* __restrict__ Cv,
                                               int M, int N, int K) {
  __shared__ unsigned short As[128 * 64];  // 16 KB
  __shared__ unsigned short Bs[128 * 64];  // 16 KB
  const int tid = threadIdx.x;
  const int wave = tid >> 6;
  const int lane = tid & 63;

  const int NT = N >> 7;
  const int id = blockIdx.x;
  const int x = id & 7;
  const int g = id >> 3;
  const int nt = g % NT;
  const int mt = x + 8 * (g / NT);
  const int bm = mt * 128;
  const int bn = nt * 128;

  const int wm = (wave >> 1) << 6;
  const int wn = (wave & 1) << 6;

  floatx4 acc[4][4] = {};

  // staging pointers: wave w covers rows 32w..32w+31 (4 chunks of 8 rows)
  const int l8 = lane >> 3;         // 0..7 (row within chunk)
  const int lk = lane & 7;          // 0..7 (physical k-group)
  const int swz = (lk ^ l8) * 8;    // swizzled global k-offset (elements)
  const unsigned short* gA = A + (size_t)(bm + 32 * wave + l8) * K + swz;
  const unsigned short* gB = B + (size_t)(bn + 32 * wave + l8) * K + swz;
  unsigned short* sAw = &As[wave * 4 * 512];
  unsigned short* sBw = &Bs[wave * 4 * 512];

  const int row16 = lane & 15, quad = lane >> 4;
  const int key = lane & 7;  // row_idx & 7 for all fragment rows

  for (int kt = 0; kt < K; kt += 64) {
    __syncthreads();
#pragma unroll
    for (int j = 0; j < 4; j++) {
      stage16(gA + (size_t)j * 8 * K, sAw + j * 512, lane);
      stage16(gB + (size_t)j * 8 * K, sBw + j * 512, lane);
    }
    gA += 64; gB += 64;
    __syncthreads();

#pragma unroll
    for (int s = 0; s < 2; s++) {
      bf16x8 af[4], bfr[4];
#pragma unroll
      for (int i = 0; i < 4; i++)
        af[i] = *(const bf16x8*)&As[(wm + i * 16 + row16) * 64 + (((s << 2) | quad) ^ key) * 8];
#pragma unroll
      for (int j = 0; j < 4; j++)
        bfr[j] = *(const bf16x8*)&Bs[(wn + j * 16 + row16) * 64 + (((s << 2) | quad) ^ key) * 8];
#pragma unroll
      for (int i = 0; i < 4; i++)
#pragma unroll
        for (int j = 0; j < 4; j++)
          acc[i][j] = __builtin_amdgcn_mfma_f32_16x16x32_bf16(af[i], bfr[j], acc[i][j], 0, 0, 0);
    }
  }

  // epilogue: C/D layout col=lane&15, row=quad*4+reg
#pragma unroll
  for (int j = 0; j < 4; j++) {
    const int gcol = bn + wn + j * 16 + row16;
    const float bb = bias ? bias[gcol] : 0.0f;
#pragma unroll
    for (int i = 0; i < 4; i++) {
      const int grow = bm + wm + i * 16 + quad * 4;
#pragma unroll
      for (int r = 0; r < 4; r++) {
        float v = acc[i][j][r] + bb;
        if (OUT_BF16)
          ((unsigned short*)Cv)[(size_t)(grow + r) * N + gcol] = f2bf(v);
        else
          ((float*)Cv)[(size_t)(grow + r) * N + gcol] = v;
      }
    }
  }
}

// ---- scan pass 1: per-chunk partial sums (64 chunks x 64 rows) ----
// proj: [2][B=4][S=4096][1024] bf16; partial: [2][4][64][1024] f32
__global__ void scan_partial(const unsigned short* __restrict__ proj, float* __restrict__ partial) {
  const int t = blockIdx.x, chunk = blockIdx.y, b = blockIdx.z;
  const int c4 = threadIdx.x * 4;
  const unsigned short* p =
      proj + ((size_t)t * 4 + b) * 4096 * 1024 + (size_t)chunk * 64 * 1024 + c4;
  float4 s = {0.f, 0.f, 0.f, 0.f};
  for (int i = 0; i < 64; i++) {
    const ushort4 v = *(const ushort4*)(p + (size_t)i * 1024);
    s.x += bf2f(v.x); s.y += bf2f(v.y); s.z += bf2f(v.z); s.w += bf2f(v.w);
  }
  *(float4*)(partial + ((size_t)(t * 4 + b) * 64 + chunk) * 1024 + c4) = s;
}

// ---- scan pass 2: prefix + running mean + head L2-norm + pack ----
// qkn: [B*S][2048] bf16, col = t*1024 + c. Head = 64 cols = 16 lanes x 4 cols.
__global__ void scan_apply(const unsigned short* __restrict__ proj,
                           const float* __restrict__ partial,
                           unsigned short* __restrict__ qkn) {
  const int t = blockIdx.x, chunk = blockIdx.y, b = blockIdx.z;
  const int c4 = threadIdx.x * 4;
  const float* pp = partial + (size_t)(t * 4 + b) * 64 * 1024 + c4;
  float4 run = {0.f, 0.f, 0.f, 0.f};
  for (int j = 0; j < chunk; j++) {
    const float4 v = *(const float4*)(pp + (size_t)j * 1024);
    run.x += v.x; run.y += v.y; run.z += v.z; run.w += v.w;
  }
  const unsigned short* p =
      proj + ((size_t)t * 4 + b) * 4096 * 1024 + (size_t)chunk * 64 * 1024 + c4;
  unsigned short* o = qkn + (size_t)b * 4096 * 2048 + (size_t)chunk * 64 * 2048 + t * 1024 + c4;
  for (int i = 0; i < 64; i++) {
    const ushort4 v = *(const ushort4*)(p + (size_t)i * 1024);
    run.x += bf2f(v.x); run.y += bf2f(v.y); run.z += bf2f(v.z); run.w += bf2f(v.w);
    const int s = chunk * 64 + i;
    const float inv = fast_rcp((float)(s + 1));
    const float a0 = run.x * inv, a1 = run.y * inv, a2 = run.z * inv, a3 = run.w * inv;
    float sq = a0 * a0 + a1 * a1 + a2 * a2 + a3 * a3;
    sq += __shfl_xor(sq, 8);
    sq += __shfl_xor(sq, 4);
    sq += __shfl_xor(sq, 2);
    sq += __shfl_xor(sq, 1);
    const float sc = fast_rsq(fmaxf(sq, 1e-24f));
    ushort4 ov;
    ov.x = f2bf(a0 * sc); ov.y = f2bf(a1 * sc); ov.z = f2bf(a2 * sc); ov.w = f2bf(a3 * sc);
    *(ushort4*)(o + (size_t)i * 2048) = ov;
  }
}

// ---- tiny precomputes: A[t][h] = W(e/r)[h] @ Wc[:, t*32:+32]^T  (64x64 each) ----
__global__ void make_A(const float* __restrict__ We, const float* __restrict__ Wr,
                       const float* __restrict__ Wc, float* __restrict__ Asm) {
  const int t = blockIdx.x >> 4, h = blockIdx.x & 15;
  const float* W = (t ? Wr : We) + (size_t)h * 64 * 32;
  for (int e = threadIdx.x; e < 4096; e += 256) {
    const int d = e >> 6, dk = e & 63;
    float s = 0.f;
    for (int r = 0; r < 32; r++) s += W[d * 32 + r] * Wc[dk * 64 + t * 32 + r];
    Asm[(size_t)blockIdx.x * 4096 + e] = s;
  }
}

// ---- Gt[f][t*1024+h*64+d] = sum_dk A[t][h][d][dk] * Wo[f][h*64+dk] ----
__global__ void make_G(const float* __restrict__ Asm, const float* __restrict__ Wo,
                       unsigned short* __restrict__ Gt) {
  __shared__ float Ash[4096];
  const int th = blockIdx.x, t = th >> 4, h = th & 15;
  for (int e = threadIdx.x; e < 4096; e += 256) Ash[e] = Asm[(size_t)th * 4096 + e];
  __syncthreads();
  const int f = blockIdx.y * 256 + threadIdx.x;
  float wo[64];
#pragma unroll
  for (int dk = 0; dk < 64; dk++) wo[dk] = Wo[(size_t)f * 1024 + h * 64 + dk];
  for (int d = 0; d < 64; d++) {
    float s = 0.f;
#pragma unroll
    for (int dk = 0; dk < 64; dk++) s += Ash[d * 64 + dk] * wo[dk];
    Gt[(size_t)f * 2048 + t * 1024 + h * 64 + d] = f2bf(s);
  }
}

// ---- c0[f] = bo[f] + sum_j bc[j&63]*Wo[f][j]; one wave per f ----
__global__ void make_c0(const float* __restrict__ bc, const float* __restrict__ bo,
                        const float* __restrict__ Wo, float* __restrict__ c0) {
  const int f = blockIdx.x * 4 + (threadIdx.x >> 6);
  const int lane = threadIdx.x & 63;
  const float bcl = bc[lane];
  float s = 0.f;
  for (int j = lane; j < 1024; j += 64) s += bcl * Wo[(size_t)f * 1024 + j];
#pragma unroll
  for (int off = 32; off; off >>= 1) s += __shfl_xor(s, off);
  if (lane == 0) c0[f] = s + bo[f];
}

extern "C" void kernel_launch(void* const* d_in, const int* in_sizes, int n_in,
                              void* d_out, int out_size, void* d_ws, size_t ws_size,
                              hipStream_t stream) {
  const float* query = (const float*)d_in[0];
  const float* key_  = (const float*)d_in[1];
  const float* Wq = (const float*)d_in[4];
  const float* bq = (const float*)d_in[5];
  const float* Wk = (const float*)d_in[6];
  const float* bk = (const float*)d_in[7];
  const float* We = (const float*)d_in[10];
  const float* Wr = (const float*)d_in[11];
  const float* Wc = (const float*)d_in[13];
  const float* bc = (const float*)d_in[14];
  const float* Wo = (const float*)d_in[15];
  const float* bo = (const float*)d_in[16];

  // ws layout (max 76.1 MB)
  char* ws = (char*)d_ws;
  unsigned short* qkbf = (unsigned short*)ws;               // 67MB: q/k bf16, later QKn (16384x2048)
  unsigned short* Wbf  = (unsigned short*)(ws + 67108864);  // 4MB: Wq,Wk bf16
  unsigned short* Gt   = (unsigned short*)(ws + 71303168);  // 4MB: G^T (1024x2048 bf16)
  float* partial       = (float*)(ws + 71303168);           // 2MB, OVERLAYS Gt (dead before make_G)
  float* Asm           = (float*)(ws + 75497472);           // 512KB
  float* c0            = (float*)(ws + 76021760);           // 4KB

  unsigned short* proj = (unsigned short*)d_out;  // d_out as scratch for bf16 projections

  // 1) fp32 -> bf16
  cvt_bf16<<<16384, 256, 0, stream>>>(query, qkbf, 4194304);
  cvt_bf16<<<16384, 256, 0, stream>>>(key_, qkbf + 16777216, 4194304);
  cvt_bf16<<<1024, 256, 0, stream>>>(Wq, Wbf, 262144);
  cvt_bf16<<<1024, 256, 0, stream>>>(Wk, Wbf + 1048576, 262144);

  // 2) q/k projections (M=16384, N=1024, K=1024) -> bf16 proj in d_out
  gemm_bt<1><<<1024, 256, 0, stream>>>(qkbf, Wbf, bq, proj, 16384, 1024, 1024);
  gemm_bt<1><<<1024, 256, 0, stream>>>(qkbf + 16777216, Wbf + 1048576, bk,
                                       proj + 16777216, 16384, 1024, 1024);

  // 3) causal running mean + l2norm + pack into QKn
  scan_partial<<<dim3(2, 64, 4), 256, 0, stream>>>(proj, partial);
  scan_apply<<<dim3(2, 64, 4), 256, 0, stream>>>(proj, partial, qkbf);

  // 4) fold We/Wr/Wc/Wo into G (after scan: partial dead, Gt region free)
  make_A<<<32, 256, 0, stream>>>(We, Wr, Wc, Asm);
  make_G<<<dim3(32, 4), 256, 0, stream>>>(Asm, Wo, Gt);
  make_c0<<<256, 256, 0, stream>>>(bc, bo, Wo, c0);

  // 5) out = QKn @ Gt^T + c0  (M=16384, N=1024, K=2048), fp32 out
  gemm_bt<0><<<1024, 256, 0, stream>>>(qkbf, Gt, c0, (float*)d_out, 16384, 1024, 2048);
}